// Round 5
// baseline (231.484 us; speedup 1.0000x reference)
//
#include <hip/hip_runtime.h>

#define HIST_BITS 12
#define NBINS (1 << HIST_BITS)        // 4096
#define KEY_SHIFT (32 - HIST_BITS)    // 20
#define REP 4                         // LDS histogram replication factor

typedef float fx4 __attribute__((ext_vector_type(4)));
typedef unsigned long long ull;

// ws layout:
//   [0, 16384)         : unsigned hist[4096]
//   [16384, 16416)     : Ctrl
//   [16416, 16 MiB)    : uint2 candidate list (key, idx)
//   [16 MiB, +n/8+64)  : keep-bitmap (ull words; chunk c of 256 elems -> words [4c,4c+4))
struct Ctrl {
    long long k;        // number of elements to zero
    long long r1;       // residual rank inside threshold bin (zero first r1)
    int b1;             // threshold bin (-1 => zero nothing)
    unsigned counter;   // candidate list append counter
};

__device__ __forceinline__ unsigned fkey(float f) {
    unsigned u = __float_as_uint(f);
    return (u & 0x80000000u) ? ~u : (u | 0x80000000u);  // monotonic total order
}

// ---------------- K0: zero hist + ctrl ----------------
__global__ void k_zero(unsigned* __restrict__ hist, Ctrl* __restrict__ ctrl) {
    int i = blockIdx.x * blockDim.x + threadIdx.x;
    if (i < NBINS) hist[i] = 0;
    if (i == 0) {
        ctrl->k = 0; ctrl->r1 = 0; ctrl->b1 = -1; ctrl->counter = 0;
    }
}

// ---------------- K1: 4096-bin histogram, 4-way replicated LDS ----------------
__global__ void __launch_bounds__(256)
k_hist(const float* __restrict__ mask, long long n, unsigned* __restrict__ ghist) {
    __shared__ unsigned sh[NBINS * REP];   // 64 KB
    for (int i = threadIdx.x; i < NBINS * REP; i += blockDim.x) sh[i] = 0;
    __syncthreads();

    const unsigned r = threadIdx.x & (REP - 1);
    const long long n4 = n >> 2;
    const fx4* m4 = (const fx4*)mask;
    const long long S = (long long)gridDim.x * blockDim.x;
    long long i = (long long)blockIdx.x * blockDim.x + threadIdx.x;

    for (; i + 3 * S < n4; i += 4 * S) {
        fx4 a = m4[i];
        fx4 b = m4[i + S];
        fx4 c = m4[i + 2 * S];
        fx4 d = m4[i + 3 * S];
        atomicAdd(&sh[(fkey(a.x) >> KEY_SHIFT) * REP + r], 1u);
        atomicAdd(&sh[(fkey(a.y) >> KEY_SHIFT) * REP + r], 1u);
        atomicAdd(&sh[(fkey(a.z) >> KEY_SHIFT) * REP + r], 1u);
        atomicAdd(&sh[(fkey(a.w) >> KEY_SHIFT) * REP + r], 1u);
        atomicAdd(&sh[(fkey(b.x) >> KEY_SHIFT) * REP + r], 1u);
        atomicAdd(&sh[(fkey(b.y) >> KEY_SHIFT) * REP + r], 1u);
        atomicAdd(&sh[(fkey(b.z) >> KEY_SHIFT) * REP + r], 1u);
        atomicAdd(&sh[(fkey(b.w) >> KEY_SHIFT) * REP + r], 1u);
        atomicAdd(&sh[(fkey(c.x) >> KEY_SHIFT) * REP + r], 1u);
        atomicAdd(&sh[(fkey(c.y) >> KEY_SHIFT) * REP + r], 1u);
        atomicAdd(&sh[(fkey(c.z) >> KEY_SHIFT) * REP + r], 1u);
        atomicAdd(&sh[(fkey(c.w) >> KEY_SHIFT) * REP + r], 1u);
        atomicAdd(&sh[(fkey(d.x) >> KEY_SHIFT) * REP + r], 1u);
        atomicAdd(&sh[(fkey(d.y) >> KEY_SHIFT) * REP + r], 1u);
        atomicAdd(&sh[(fkey(d.z) >> KEY_SHIFT) * REP + r], 1u);
        atomicAdd(&sh[(fkey(d.w) >> KEY_SHIFT) * REP + r], 1u);
    }
    for (; i < n4; i += S) {
        fx4 a = m4[i];
        atomicAdd(&sh[(fkey(a.x) >> KEY_SHIFT) * REP + r], 1u);
        atomicAdd(&sh[(fkey(a.y) >> KEY_SHIFT) * REP + r], 1u);
        atomicAdd(&sh[(fkey(a.z) >> KEY_SHIFT) * REP + r], 1u);
        atomicAdd(&sh[(fkey(a.w) >> KEY_SHIFT) * REP + r], 1u);
    }
    if (blockIdx.x == 0 && threadIdx.x == 0) {
        for (long long t = n4 * 4; t < n; ++t)
            atomicAdd(&ghist[fkey(mask[t]) >> KEY_SHIFT], 1u);
    }
    __syncthreads();
    for (int b = threadIdx.x; b < NBINS; b += blockDim.x) {
        unsigned s = sh[b * REP] + sh[b * REP + 1] + sh[b * REP + 2] + sh[b * REP + 3];
        if (s) atomicAdd(&ghist[b], s);
    }
}

// ---------------- K2: scan histogram, find threshold bin ----------------
__global__ void k_scan(const unsigned* __restrict__ ghist, Ctrl* __restrict__ ctrl,
                       const float* __restrict__ p_ptr, long long n) {
    __shared__ long long part[256];
    __shared__ long long kk_sh;
    const int t = threadIdx.x;
    if (t == 0) {
        double p = (double)p_ptr[0];
        long long k = (long long)((1.0 - p) * (double)n);  // matches python int()
        if (k < 0) k = 0;
        if (k > n) k = n;
        kk_sh = k;
        ctrl->k = k;
        ctrl->b1 = -1;
        ctrl->r1 = 0;
    }
    __syncthreads();
    const long long k = kk_sh;

    const int per = NBINS / 256;
    long long s = 0;
    for (int i = 0; i < per; ++i) s += (long long)ghist[t * per + i];
    part[t] = s;
    __syncthreads();
    for (int off = 1; off < 256; off <<= 1) {
        long long add = (t >= off) ? part[t - off] : 0;
        __syncthreads();
        part[t] += add;
        __syncthreads();
    }
    if (k >= 1) {
        long long incl = part[t];
        long long excl = incl - s;
        if (excl < k && k <= incl) {
            long long cum = excl;
            for (int i = 0; i < per; ++i) {
                long long c = (long long)ghist[t * per + i];
                if (cum < k && k <= cum + c) {
                    ctrl->b1 = t * per + i;
                    ctrl->r1 = k - cum;
                    break;
                }
                cum += c;
            }
        }
    }
}

// ---------------- K2.5: keep-bitmap from L3-resident mask + candidates ----------------
__global__ void __launch_bounds__(256)
k_bm(const float* __restrict__ mask, long long n, Ctrl* __restrict__ ctrl,
     ull* __restrict__ bm, uint2* __restrict__ list, unsigned cap) {
    const int b1 = ctrl->b1;
    const long long n4 = n >> 2;
    const long long chunks = (n4 + 63) >> 6;
    const fx4* m4 = (const fx4*)mask;
    const int lane = threadIdx.x & 63;
    const long long wid = (long long)blockIdx.x * (blockDim.x >> 6) + (threadIdx.x >> 6);
    const long long nw = (long long)gridDim.x * (blockDim.x >> 6);

    for (long long ch = wid; ch < chunks; ch += nw) {
        long long g = ch * 64 + lane;
        bool valid = g < n4;
        fx4 m;
        if (valid) m = m4[g]; else { m.x = m.y = m.z = m.w = 0.0f; }
        unsigned kx = fkey(m.x), ky = fkey(m.y), kz = fkey(m.z), kw = fkey(m.w);
        int bx = (int)(kx >> KEY_SHIFT), by = (int)(ky >> KEY_SHIFT);
        int bz = (int)(kz >> KEY_SHIFT), bw = (int)(kw >> KEY_SHIFT);
        if (valid) {
            unsigned base = (unsigned)(g * 4);
            if (bx == b1) { unsigned p = atomicAdd(&ctrl->counter, 1u); if (p < cap) list[p] = make_uint2(kx, base + 0); }
            if (by == b1) { unsigned p = atomicAdd(&ctrl->counter, 1u); if (p < cap) list[p] = make_uint2(ky, base + 1); }
            if (bz == b1) { unsigned p = atomicAdd(&ctrl->counter, 1u); if (p < cap) list[p] = make_uint2(kz, base + 2); }
            if (bw == b1) { unsigned p = atomicAdd(&ctrl->counter, 1u); if (p < cap) list[p] = make_uint2(kw, base + 3); }
        }
        ull w0 = __ballot(bx >= b1);
        ull w1 = __ballot(by >= b1);
        ull w2 = __ballot(bz >= b1);
        ull w3 = __ballot(bw >= b1);
        if (lane < 4) {
            ull w = (lane == 0) ? w0 : (lane == 1) ? w1 : (lane == 2) ? w2 : w3;
            bm[ch * 4 + lane] = w;
        }
    }
    // scalar tail: candidates only (k_apply tail classifies from mask directly)
    if (blockIdx.x == 0 && threadIdx.x == 0) {
        for (long long t = n4 * 4; t < n; ++t) {
            unsigned key = fkey(mask[t]);
            if ((int)(key >> KEY_SHIFT) == b1) {
                unsigned p = atomicAdd(&ctrl->counter, 1u);
                if (p < cap) list[p] = make_uint2(key, (unsigned)t);
            }
        }
    }
}

// ---------------- K3: pure 2-stream apply via bitmap ----------------
__global__ void __launch_bounds__(256)
k_apply_bm(const float* __restrict__ w, const ull* __restrict__ bm,
           const float* __restrict__ mask, float* __restrict__ out, long long n,
           const Ctrl* __restrict__ ctrl) {
    const long long n4 = n >> 2;
    const long long chunks = (n4 + 63) >> 6;
    const fx4* w4 = (const fx4*)w;
    fx4* o4 = (fx4*)out;
    const int lane = threadIdx.x & 63;
    const ull lm = 1ull << lane;
    const long long wid = (long long)blockIdx.x * (blockDim.x >> 6) + (threadIdx.x >> 6);
    const long long nw = (long long)gridDim.x * (blockDim.x >> 6);

    long long ch = wid;
    for (; ch + nw < chunks; ch += 2 * nw) {
        long long g0 = ch * 64 + lane;
        long long g1 = (ch + nw) * 64 + lane;
        fx4 wa, wb;
        if (g0 < n4) wa = __builtin_nontemporal_load(&w4[g0]);
        if (g1 < n4) wb = __builtin_nontemporal_load(&w4[g1]);
        ull a0 = bm[ch * 4 + 0], a1 = bm[ch * 4 + 1], a2 = bm[ch * 4 + 2], a3 = bm[ch * 4 + 3];
        ull b0 = bm[(ch + nw) * 4 + 0], b1v = bm[(ch + nw) * 4 + 1];
        ull b2 = bm[(ch + nw) * 4 + 2], b3 = bm[(ch + nw) * 4 + 3];
        if (g0 < n4) {
            fx4 o;
            o.x = (a0 & lm) ? wa.x : 0.0f;
            o.y = (a1 & lm) ? wa.y : 0.0f;
            o.z = (a2 & lm) ? wa.z : 0.0f;
            o.w = (a3 & lm) ? wa.w : 0.0f;
            __builtin_nontemporal_store(o, &o4[g0]);
        }
        if (g1 < n4) {
            fx4 o;
            o.x = (b0 & lm) ? wb.x : 0.0f;
            o.y = (b1v & lm) ? wb.y : 0.0f;
            o.z = (b2 & lm) ? wb.z : 0.0f;
            o.w = (b3 & lm) ? wb.w : 0.0f;
            __builtin_nontemporal_store(o, &o4[g1]);
        }
    }
    for (; ch < chunks; ch += nw) {
        long long g = ch * 64 + lane;
        if (g < n4) {
            fx4 wv = __builtin_nontemporal_load(&w4[g]);
            ull a0 = bm[ch * 4 + 0], a1 = bm[ch * 4 + 1], a2 = bm[ch * 4 + 2], a3 = bm[ch * 4 + 3];
            fx4 o;
            o.x = (a0 & lm) ? wv.x : 0.0f;
            o.y = (a1 & lm) ? wv.y : 0.0f;
            o.z = (a2 & lm) ? wv.z : 0.0f;
            o.w = (a3 & lm) ? wv.w : 0.0f;
            __builtin_nontemporal_store(o, &o4[g]);
        }
    }
    // tail: classify from mask directly (no candidate appends here)
    if (blockIdx.x == 0 && threadIdx.x == 0) {
        const int b1 = ctrl->b1;
        for (long long t = n4 * 4; t < n; ++t) {
            int bin = (int)(fkey(mask[t]) >> KEY_SHIFT);
            out[t] = (bin < b1) ? 0.0f : w[t];
        }
    }
}

// ---------------- K3-fallback: apply reading mask (R4 path, ws too small) ----------------
__device__ __forceinline__ float apply1(float m, float w, unsigned idx, int b1,
                                        Ctrl* ctrl, uint2* list, unsigned cap) {
    unsigned key = fkey(m);
    int bin = (int)(key >> KEY_SHIFT);
    if (bin < b1) return 0.0f;
    if (bin == b1) {
        unsigned pos = atomicAdd(&ctrl->counter, 1u);
        if (pos < cap) list[pos] = make_uint2(key, idx);
    }
    return w;
}

__global__ void __launch_bounds__(256)
k_apply_mask(const float* __restrict__ w, const float* __restrict__ mask,
             float* __restrict__ out, long long n,
             Ctrl* __restrict__ ctrl, uint2* __restrict__ list, unsigned cap) {
    const int b1 = ctrl->b1;
    const long long n4 = n >> 2;
    const fx4* m4 = (const fx4*)mask;
    const fx4* w4 = (const fx4*)w;
    fx4* o4 = (fx4*)out;
    const long long S = (long long)gridDim.x * blockDim.x;
    long long i = (long long)blockIdx.x * blockDim.x + threadIdx.x;
    for (; i < n4; i += S) {
        fx4 m0 = m4[i];
        fx4 w0 = __builtin_nontemporal_load(&w4[i]);
        fx4 o0;
        unsigned base0 = (unsigned)(i * 4);
        o0.x = apply1(m0.x, w0.x, base0 + 0, b1, ctrl, list, cap);
        o0.y = apply1(m0.y, w0.y, base0 + 1, b1, ctrl, list, cap);
        o0.z = apply1(m0.z, w0.z, base0 + 2, b1, ctrl, list, cap);
        o0.w = apply1(m0.w, w0.w, base0 + 3, b1, ctrl, list, cap);
        __builtin_nontemporal_store(o0, &o4[i]);
    }
    if (blockIdx.x == 0 && threadIdx.x == 0) {
        for (long long t = n4 * 4; t < n; ++t)
            out[t] = apply1(mask[t], w[t], (unsigned)t, b1, ctrl, list, cap);
    }
}

// ---------------- K4: exact rank among candidates, zero first r1 ----------------
__global__ void k_fix(float* __restrict__ out, const Ctrl* __restrict__ ctrl,
                      const uint2* __restrict__ list, unsigned cap) {
    __shared__ uint2 ch[1024];
    unsigned nc = ctrl->counter;
    if (nc > cap) nc = cap;
    const long long r1 = ctrl->r1;
    if (ctrl->b1 < 0 || r1 <= 0) return;

    for (unsigned jb = 0; jb < nc; jb += blockDim.x) {
        unsigned j = jb + threadIdx.x;
        bool act = (j < nc);
        unsigned kj = 0, ij = 0;
        if (act) { uint2 e = list[j]; kj = e.x; ij = e.y; }
        long long rank = 0;
        for (unsigned cb = 0; cb < nc; cb += 1024) {
            unsigned mlen = nc - cb; if (mlen > 1024) mlen = 1024;
            for (unsigned u = threadIdx.x; u < mlen; u += blockDim.x) ch[u] = list[cb + u];
            __syncthreads();
            if (act) {
                for (unsigned u = 0; u < mlen; ++u) {
                    uint2 e = ch[u];
                    rank += (long long)((e.x < kj) || (e.x == kj && e.y < ij));
                }
            }
            __syncthreads();
        }
        if (act && rank < r1) out[ij] = 0.0f;
    }
}

extern "C" void kernel_launch(void* const* d_in, const int* in_sizes, int n_in,
                              void* d_out, int out_size, void* d_ws, size_t ws_size,
                              hipStream_t stream) {
    const float* weight = (const float*)d_in[0];
    const float* maskw  = (const float*)d_in[1];
    const float* pptr   = (const float*)d_in[2];
    float* out = (float*)d_out;
    const long long n = (long long)in_sizes[0];

    unsigned char* ws = (unsigned char*)d_ws;
    unsigned* hist = (unsigned*)ws;
    Ctrl* ctrl = (Ctrl*)(ws + 16384);
    uint2* list = (uint2*)(ws + 16416);
    const size_t BM_OFF = (size_t)16 << 20;  // 16 MiB
    unsigned cap = (unsigned)((BM_OFF - 16416) / sizeof(uint2));

    const long long n4 = n >> 2;
    const long long chunks = (n4 + 63) >> 6;
    const size_t bm_bytes = (size_t)chunks * 4 * sizeof(ull);
    const bool use_bm = ws_size >= BM_OFF + bm_bytes + 64;
    ull* bm = (ull*)(ws + BM_OFF);

    k_zero<<<(NBINS + 255) / 256, 256, 0, stream>>>(hist, ctrl);
    k_hist<<<2048, 256, 0, stream>>>(maskw, n, hist);
    k_scan<<<1, 256, 0, stream>>>(hist, ctrl, pptr, n);
    if (use_bm) {
        k_bm<<<2048, 256, 0, stream>>>(maskw, n, ctrl, bm, list, cap);
        k_apply_bm<<<2048, 256, 0, stream>>>(weight, bm, maskw, out, n, ctrl);
    } else {
        size_t cap_sz = (ws_size > 16416) ? (ws_size - 16416) / sizeof(uint2) : 0;
        unsigned cap2 = (unsigned)(cap_sz > (size_t)(1u << 20) ? (1u << 20) : cap_sz);
        k_apply_mask<<<2048, 256, 0, stream>>>(weight, maskw, out, n, ctrl, list, cap2);
    }
    k_fix<<<1, 256, 0, stream>>>(out, ctrl, list, cap);
}

// Round 6
// 201.820 us; speedup vs baseline: 1.1470x; 1.1470x over previous
//
#include <hip/hip_runtime.h>

#define HIST_BITS 12
#define NBINS (1 << HIST_BITS)        // 4096
#define KEY_SHIFT (32 - HIST_BITS)    // 20
#define REP 4                         // LDS histogram replication factor

typedef float fx4 __attribute__((ext_vector_type(4)));

// ws layout:
//   [0, 16384)     : unsigned hist[4096]
//   [16384, 16416) : Ctrl
//   [16416, ...)   : uint2 candidate list (key, idx)
struct Ctrl {
    long long k;        // number of elements to zero
    long long r1;       // residual rank inside threshold bin (zero first r1)
    int b1;             // threshold bin (-1 => zero nothing)
    unsigned counter;   // candidate list append counter
};

__device__ __forceinline__ unsigned fkey(float f) {
    unsigned u = __float_as_uint(f);
    return (u & 0x80000000u) ? ~u : (u | 0x80000000u);  // monotonic total order
}

// ---------------- K0: zero hist + ctrl ----------------
__global__ void k_zero(unsigned* __restrict__ hist, Ctrl* __restrict__ ctrl) {
    int i = blockIdx.x * blockDim.x + threadIdx.x;
    if (i < NBINS) hist[i] = 0;
    if (i == 0) {
        ctrl->k = 0; ctrl->r1 = 0; ctrl->b1 = -1; ctrl->counter = 0;
    }
}

// ---------------- K1: 4096-bin histogram, 4-way replicated LDS, 1024 thr ----------------
__global__ void __launch_bounds__(1024)
k_hist(const float* __restrict__ mask, long long n, unsigned* __restrict__ ghist) {
    __shared__ unsigned sh[NBINS * REP];   // 64 KB: layout bin*REP + r
    for (int i = threadIdx.x; i < NBINS * REP; i += blockDim.x) sh[i] = 0;
    __syncthreads();

    const unsigned r = threadIdx.x & (REP - 1);
    const long long n4 = n >> 2;
    const fx4* m4 = (const fx4*)mask;
    const long long S = (long long)gridDim.x * blockDim.x;
    long long i = (long long)blockIdx.x * blockDim.x + threadIdx.x;

    for (; i + 3 * S < n4; i += 4 * S) {
        fx4 a = m4[i];
        fx4 b = m4[i + S];
        fx4 c = m4[i + 2 * S];
        fx4 d = m4[i + 3 * S];
        atomicAdd(&sh[(fkey(a.x) >> KEY_SHIFT) * REP + r], 1u);
        atomicAdd(&sh[(fkey(a.y) >> KEY_SHIFT) * REP + r], 1u);
        atomicAdd(&sh[(fkey(a.z) >> KEY_SHIFT) * REP + r], 1u);
        atomicAdd(&sh[(fkey(a.w) >> KEY_SHIFT) * REP + r], 1u);
        atomicAdd(&sh[(fkey(b.x) >> KEY_SHIFT) * REP + r], 1u);
        atomicAdd(&sh[(fkey(b.y) >> KEY_SHIFT) * REP + r], 1u);
        atomicAdd(&sh[(fkey(b.z) >> KEY_SHIFT) * REP + r], 1u);
        atomicAdd(&sh[(fkey(b.w) >> KEY_SHIFT) * REP + r], 1u);
        atomicAdd(&sh[(fkey(c.x) >> KEY_SHIFT) * REP + r], 1u);
        atomicAdd(&sh[(fkey(c.y) >> KEY_SHIFT) * REP + r], 1u);
        atomicAdd(&sh[(fkey(c.z) >> KEY_SHIFT) * REP + r], 1u);
        atomicAdd(&sh[(fkey(c.w) >> KEY_SHIFT) * REP + r], 1u);
        atomicAdd(&sh[(fkey(d.x) >> KEY_SHIFT) * REP + r], 1u);
        atomicAdd(&sh[(fkey(d.y) >> KEY_SHIFT) * REP + r], 1u);
        atomicAdd(&sh[(fkey(d.z) >> KEY_SHIFT) * REP + r], 1u);
        atomicAdd(&sh[(fkey(d.w) >> KEY_SHIFT) * REP + r], 1u);
    }
    for (; i < n4; i += S) {
        fx4 a = m4[i];
        atomicAdd(&sh[(fkey(a.x) >> KEY_SHIFT) * REP + r], 1u);
        atomicAdd(&sh[(fkey(a.y) >> KEY_SHIFT) * REP + r], 1u);
        atomicAdd(&sh[(fkey(a.z) >> KEY_SHIFT) * REP + r], 1u);
        atomicAdd(&sh[(fkey(a.w) >> KEY_SHIFT) * REP + r], 1u);
    }
    if (blockIdx.x == 0 && threadIdx.x == 0) {
        for (long long t = n4 * 4; t < n; ++t)
            atomicAdd(&ghist[fkey(mask[t]) >> KEY_SHIFT], 1u);
    }
    __syncthreads();
    for (int b = threadIdx.x; b < NBINS; b += blockDim.x) {
        unsigned s = sh[b * REP] + sh[b * REP + 1] + sh[b * REP + 2] + sh[b * REP + 3];
        if (s) atomicAdd(&ghist[b], s);
    }
}

// ---------------- K2: scan histogram, find threshold bin ----------------
__global__ void k_scan(const unsigned* __restrict__ ghist, Ctrl* __restrict__ ctrl,
                       const float* __restrict__ p_ptr, long long n) {
    __shared__ long long part[256];
    __shared__ long long kk_sh;
    const int t = threadIdx.x;
    if (t == 0) {
        double p = (double)p_ptr[0];
        long long k = (long long)((1.0 - p) * (double)n);  // matches python int()
        if (k < 0) k = 0;
        if (k > n) k = n;
        kk_sh = k;
        ctrl->k = k;
        ctrl->b1 = -1;
        ctrl->r1 = 0;
    }
    __syncthreads();
    const long long k = kk_sh;

    const int per = NBINS / 256;
    long long s = 0;
    for (int i = 0; i < per; ++i) s += (long long)ghist[t * per + i];
    part[t] = s;
    __syncthreads();
    for (int off = 1; off < 256; off <<= 1) {
        long long add = (t >= off) ? part[t - off] : 0;
        __syncthreads();
        part[t] += add;
        __syncthreads();
    }
    if (k >= 1) {
        long long incl = part[t];
        long long excl = incl - s;
        if (excl < k && k <= incl) {
            long long cum = excl;
            for (int i = 0; i < per; ++i) {
                long long c = (long long)ghist[t * per + i];
                if (cum < k && k <= cum + c) {
                    ctrl->b1 = t * per + i;
                    ctrl->r1 = k - cum;
                    break;
                }
                cum += c;
            }
        }
    }
}

// ---------------- K3: fused apply + candidate collection (R4 structure, ILP 4) ----------------
__device__ __forceinline__ float apply1(float m, float w, unsigned idx, int b1,
                                        Ctrl* ctrl, uint2* list, unsigned cap) {
    unsigned key = fkey(m);
    int bin = (int)(key >> KEY_SHIFT);
    if (bin < b1) return 0.0f;
    if (bin == b1) {
        unsigned pos = atomicAdd(&ctrl->counter, 1u);
        if (pos < cap) list[pos] = make_uint2(key, idx);
    }
    return w;
}

__global__ void __launch_bounds__(256)
k_apply(const float* __restrict__ w, const float* __restrict__ mask,
        float* __restrict__ out, long long n,
        Ctrl* __restrict__ ctrl, uint2* __restrict__ list, unsigned cap) {
    const int b1 = ctrl->b1;
    const long long n4 = n >> 2;
    const fx4* m4 = (const fx4*)mask;
    const fx4* w4 = (const fx4*)w;
    fx4* o4 = (fx4*)out;
    const long long S = (long long)gridDim.x * blockDim.x;
    long long i = (long long)blockIdx.x * blockDim.x + threadIdx.x;

    // 4x ILP: 8 independent loads in flight; mask cached (L3), weight NT, out NT
    for (; i + 3 * S < n4; i += 4 * S) {
        fx4 m0 = m4[i];
        fx4 m1 = m4[i + S];
        fx4 m2 = m4[i + 2 * S];
        fx4 m3 = m4[i + 3 * S];
        fx4 w0 = __builtin_nontemporal_load(&w4[i]);
        fx4 w1 = __builtin_nontemporal_load(&w4[i + S]);
        fx4 w2 = __builtin_nontemporal_load(&w4[i + 2 * S]);
        fx4 w3 = __builtin_nontemporal_load(&w4[i + 3 * S]);
        unsigned base0 = (unsigned)(i * 4);
        unsigned base1 = (unsigned)((i + S) * 4);
        unsigned base2 = (unsigned)((i + 2 * S) * 4);
        unsigned base3 = (unsigned)((i + 3 * S) * 4);
        fx4 o0, o1, o2, o3;
        o0.x = apply1(m0.x, w0.x, base0 + 0, b1, ctrl, list, cap);
        o0.y = apply1(m0.y, w0.y, base0 + 1, b1, ctrl, list, cap);
        o0.z = apply1(m0.z, w0.z, base0 + 2, b1, ctrl, list, cap);
        o0.w = apply1(m0.w, w0.w, base0 + 3, b1, ctrl, list, cap);
        o1.x = apply1(m1.x, w1.x, base1 + 0, b1, ctrl, list, cap);
        o1.y = apply1(m1.y, w1.y, base1 + 1, b1, ctrl, list, cap);
        o1.z = apply1(m1.z, w1.z, base1 + 2, b1, ctrl, list, cap);
        o1.w = apply1(m1.w, w1.w, base1 + 3, b1, ctrl, list, cap);
        o2.x = apply1(m2.x, w2.x, base2 + 0, b1, ctrl, list, cap);
        o2.y = apply1(m2.y, w2.y, base2 + 1, b1, ctrl, list, cap);
        o2.z = apply1(m2.z, w2.z, base2 + 2, b1, ctrl, list, cap);
        o2.w = apply1(m2.w, w2.w, base2 + 3, b1, ctrl, list, cap);
        o3.x = apply1(m3.x, w3.x, base3 + 0, b1, ctrl, list, cap);
        o3.y = apply1(m3.y, w3.y, base3 + 1, b1, ctrl, list, cap);
        o3.z = apply1(m3.z, w3.z, base3 + 2, b1, ctrl, list, cap);
        o3.w = apply1(m3.w, w3.w, base3 + 3, b1, ctrl, list, cap);
        __builtin_nontemporal_store(o0, &o4[i]);
        __builtin_nontemporal_store(o1, &o4[i + S]);
        __builtin_nontemporal_store(o2, &o4[i + 2 * S]);
        __builtin_nontemporal_store(o3, &o4[i + 3 * S]);
    }
    for (; i < n4; i += S) {
        fx4 m0 = m4[i];
        fx4 w0 = __builtin_nontemporal_load(&w4[i]);
        fx4 o0;
        unsigned base0 = (unsigned)(i * 4);
        o0.x = apply1(m0.x, w0.x, base0 + 0, b1, ctrl, list, cap);
        o0.y = apply1(m0.y, w0.y, base0 + 1, b1, ctrl, list, cap);
        o0.z = apply1(m0.z, w0.z, base0 + 2, b1, ctrl, list, cap);
        o0.w = apply1(m0.w, w0.w, base0 + 3, b1, ctrl, list, cap);
        __builtin_nontemporal_store(o0, &o4[i]);
    }
    if (blockIdx.x == 0 && threadIdx.x == 0) {
        for (long long t = n4 * 4; t < n; ++t)
            out[t] = apply1(mask[t], w[t], (unsigned)t, b1, ctrl, list, cap);
    }
}

// ---------------- K4: exact rank among candidates, zero first r1 ----------------
__global__ void k_fix(float* __restrict__ out, const Ctrl* __restrict__ ctrl,
                      const uint2* __restrict__ list, unsigned cap) {
    __shared__ uint2 ch[1024];
    unsigned nc = ctrl->counter;
    if (nc > cap) nc = cap;
    const long long r1 = ctrl->r1;
    if (ctrl->b1 < 0 || r1 <= 0) return;

    for (unsigned jb = 0; jb < nc; jb += blockDim.x) {
        unsigned j = jb + threadIdx.x;
        bool act = (j < nc);
        unsigned kj = 0, ij = 0;
        if (act) { uint2 e = list[j]; kj = e.x; ij = e.y; }
        long long rank = 0;
        for (unsigned cb = 0; cb < nc; cb += 1024) {
            unsigned mlen = nc - cb; if (mlen > 1024) mlen = 1024;
            for (unsigned u = threadIdx.x; u < mlen; u += blockDim.x) ch[u] = list[cb + u];
            __syncthreads();
            if (act) {
                for (unsigned u = 0; u < mlen; ++u) {
                    uint2 e = ch[u];
                    rank += (long long)((e.x < kj) || (e.x == kj && e.y < ij));
                }
            }
            __syncthreads();
        }
        if (act && rank < r1) out[ij] = 0.0f;
    }
}

extern "C" void kernel_launch(void* const* d_in, const int* in_sizes, int n_in,
                              void* d_out, int out_size, void* d_ws, size_t ws_size,
                              hipStream_t stream) {
    const float* weight = (const float*)d_in[0];
    const float* maskw  = (const float*)d_in[1];
    const float* pptr   = (const float*)d_in[2];
    float* out = (float*)d_out;
    const long long n = (long long)in_sizes[0];

    unsigned char* ws = (unsigned char*)d_ws;
    unsigned* hist = (unsigned*)ws;
    Ctrl* ctrl = (Ctrl*)(ws + 16384);
    uint2* list = (uint2*)(ws + 16416);
    size_t cap_sz = (ws_size > 16416) ? (ws_size - 16416) / sizeof(uint2) : 0;
    unsigned cap = (unsigned)(cap_sz > (size_t)(1u << 20) ? (1u << 20) : cap_sz);

    k_zero<<<(NBINS + 255) / 256, 256, 0, stream>>>(hist, ctrl);
    k_hist<<<512, 1024, 0, stream>>>(maskw, n, hist);
    k_scan<<<1, 256, 0, stream>>>(hist, ctrl, pptr, n);
    k_apply<<<2048, 256, 0, stream>>>(weight, maskw, out, n, ctrl, list, cap);
    k_fix<<<1, 256, 0, stream>>>(out, ctrl, list, cap);
}

// Round 7
// 185.072 us; speedup vs baseline: 1.2508x; 1.0905x over previous
//
#include <hip/hip_runtime.h>

#define HIST_BITS 12
#define NBINS (1 << HIST_BITS)        // 4096
#define KEY_SHIFT (32 - HIST_BITS)    // 20
#define REP 4                         // LDS histogram replication factor

typedef float fx4 __attribute__((ext_vector_type(4)));

// ws layout:
//   [0, 16384)     : unsigned hist[4096]
//   [16384, 16416) : Ctrl
//   [16416, ...)   : uint2 candidate list (key, idx)
struct Ctrl {
    long long k;        // number of elements to zero
    long long r1;       // residual rank inside threshold bin (zero first r1)
    int b1;             // threshold bin (-1 => zero nothing)
    unsigned counter;   // candidate list append counter
};

__device__ __forceinline__ unsigned fkey(float f) {
    unsigned u = __float_as_uint(f);
    return (u & 0x80000000u) ? ~u : (u | 0x80000000u);  // monotonic total order
}

// ---------------- K0: zero hist + ctrl ----------------
__global__ void k_zero(unsigned* __restrict__ hist, Ctrl* __restrict__ ctrl) {
    int i = blockIdx.x * blockDim.x + threadIdx.x;
    if (i < NBINS) hist[i] = 0;
    if (i == 0) {
        ctrl->k = 0; ctrl->r1 = 0; ctrl->b1 = -1; ctrl->counter = 0;
    }
}

// ---------------- K1: histogram, block-tiled contiguous, 4-way replicated LDS ----------------
__global__ void __launch_bounds__(1024)
k_hist(const float* __restrict__ mask, long long n, unsigned* __restrict__ ghist) {
    __shared__ unsigned sh[NBINS * REP];   // 64 KB: layout bin*REP + r
    for (int i = threadIdx.x; i < NBINS * REP; i += blockDim.x) sh[i] = 0;
    __syncthreads();

    const unsigned r = threadIdx.x & (REP - 1);
    const long long n4 = n >> 2;
    const fx4* m4 = (const fx4*)mask;
    const long long B = blockDim.x;
    const long long per = (n4 + gridDim.x - 1) / gridDim.x;   // fx4 per block (contiguous tile)
    const long long s0 = (long long)blockIdx.x * per;
    const long long e = (s0 + per < n4) ? s0 + per : n4;

    long long i = s0 + threadIdx.x;
    for (; i + 3 * B < e; i += 4 * B) {
        fx4 a = m4[i];
        fx4 b = m4[i + B];
        fx4 c = m4[i + 2 * B];
        fx4 d = m4[i + 3 * B];
        atomicAdd(&sh[(fkey(a.x) >> KEY_SHIFT) * REP + r], 1u);
        atomicAdd(&sh[(fkey(a.y) >> KEY_SHIFT) * REP + r], 1u);
        atomicAdd(&sh[(fkey(a.z) >> KEY_SHIFT) * REP + r], 1u);
        atomicAdd(&sh[(fkey(a.w) >> KEY_SHIFT) * REP + r], 1u);
        atomicAdd(&sh[(fkey(b.x) >> KEY_SHIFT) * REP + r], 1u);
        atomicAdd(&sh[(fkey(b.y) >> KEY_SHIFT) * REP + r], 1u);
        atomicAdd(&sh[(fkey(b.z) >> KEY_SHIFT) * REP + r], 1u);
        atomicAdd(&sh[(fkey(b.w) >> KEY_SHIFT) * REP + r], 1u);
        atomicAdd(&sh[(fkey(c.x) >> KEY_SHIFT) * REP + r], 1u);
        atomicAdd(&sh[(fkey(c.y) >> KEY_SHIFT) * REP + r], 1u);
        atomicAdd(&sh[(fkey(c.z) >> KEY_SHIFT) * REP + r], 1u);
        atomicAdd(&sh[(fkey(c.w) >> KEY_SHIFT) * REP + r], 1u);
        atomicAdd(&sh[(fkey(d.x) >> KEY_SHIFT) * REP + r], 1u);
        atomicAdd(&sh[(fkey(d.y) >> KEY_SHIFT) * REP + r], 1u);
        atomicAdd(&sh[(fkey(d.z) >> KEY_SHIFT) * REP + r], 1u);
        atomicAdd(&sh[(fkey(d.w) >> KEY_SHIFT) * REP + r], 1u);
    }
    for (; i < e; i += B) {
        fx4 a = m4[i];
        atomicAdd(&sh[(fkey(a.x) >> KEY_SHIFT) * REP + r], 1u);
        atomicAdd(&sh[(fkey(a.y) >> KEY_SHIFT) * REP + r], 1u);
        atomicAdd(&sh[(fkey(a.z) >> KEY_SHIFT) * REP + r], 1u);
        atomicAdd(&sh[(fkey(a.w) >> KEY_SHIFT) * REP + r], 1u);
    }
    if (blockIdx.x == 0 && threadIdx.x == 0) {
        for (long long t = n4 * 4; t < n; ++t)
            atomicAdd(&ghist[fkey(mask[t]) >> KEY_SHIFT], 1u);
    }
    __syncthreads();
    for (int b = threadIdx.x; b < NBINS; b += blockDim.x) {
        unsigned s = sh[b * REP] + sh[b * REP + 1] + sh[b * REP + 2] + sh[b * REP + 3];
        if (s) atomicAdd(&ghist[b], s);
    }
}

// ---------------- K2: scan histogram, find threshold bin ----------------
__global__ void k_scan(const unsigned* __restrict__ ghist, Ctrl* __restrict__ ctrl,
                       const float* __restrict__ p_ptr, long long n) {
    __shared__ long long part[256];
    __shared__ long long kk_sh;
    const int t = threadIdx.x;
    if (t == 0) {
        double p = (double)p_ptr[0];
        long long k = (long long)((1.0 - p) * (double)n);  // matches python int()
        if (k < 0) k = 0;
        if (k > n) k = n;
        kk_sh = k;
        ctrl->k = k;
        ctrl->b1 = -1;
        ctrl->r1 = 0;
    }
    __syncthreads();
    const long long k = kk_sh;

    const int per = NBINS / 256;
    long long s = 0;
    for (int i = 0; i < per; ++i) s += (long long)ghist[t * per + i];
    part[t] = s;
    __syncthreads();
    for (int off = 1; off < 256; off <<= 1) {
        long long add = (t >= off) ? part[t - off] : 0;
        __syncthreads();
        part[t] += add;
        __syncthreads();
    }
    if (k >= 1) {
        long long incl = part[t];
        long long excl = incl - s;
        if (excl < k && k <= incl) {
            long long cum = excl;
            for (int i = 0; i < per; ++i) {
                long long c = (long long)ghist[t * per + i];
                if (cum < k && k <= cum + c) {
                    ctrl->b1 = t * per + i;
                    ctrl->r1 = k - cum;
                    break;
                }
                cum += c;
            }
        }
    }
}

// ---------------- K3: fused apply, block-tiled contiguous, ILP4 ----------------
__device__ __forceinline__ void cand4(unsigned k0, unsigned k1, unsigned k2, unsigned k3,
                                      unsigned base, unsigned b1u,
                                      Ctrl* ctrl, uint2* list, unsigned cap) {
    if ((k0 >> KEY_SHIFT) == b1u) { unsigned p = atomicAdd(&ctrl->counter, 1u); if (p < cap) list[p] = make_uint2(k0, base + 0); }
    if ((k1 >> KEY_SHIFT) == b1u) { unsigned p = atomicAdd(&ctrl->counter, 1u); if (p < cap) list[p] = make_uint2(k1, base + 1); }
    if ((k2 >> KEY_SHIFT) == b1u) { unsigned p = atomicAdd(&ctrl->counter, 1u); if (p < cap) list[p] = make_uint2(k2, base + 2); }
    if ((k3 >> KEY_SHIFT) == b1u) { unsigned p = atomicAdd(&ctrl->counter, 1u); if (p < cap) list[p] = make_uint2(k3, base + 3); }
}

__global__ void __launch_bounds__(256)
k_apply(const float* __restrict__ w, const float* __restrict__ mask,
        float* __restrict__ out, long long n,
        Ctrl* __restrict__ ctrl, uint2* __restrict__ list, unsigned cap) {
    const int b1 = ctrl->b1;
    const unsigned b1u = (unsigned)b1;                                   // ==bin never true for b1=-1
    const unsigned lo = (b1 <= 0) ? 0u : ((unsigned)b1 << KEY_SHIFT);    // keep iff key >= lo
    const long long n4 = n >> 2;
    const fx4* m4 = (const fx4*)mask;
    const fx4* w4 = (const fx4*)w;
    fx4* o4 = (fx4*)out;
    const long long B = blockDim.x;
    const long long per = (n4 + gridDim.x - 1) / gridDim.x;   // fx4 per block (contiguous tile)
    const long long s0 = (long long)blockIdx.x * per;
    const long long e = (s0 + per < n4) ? s0 + per : n4;

    long long i = s0 + threadIdx.x;
    for (; i + 3 * B < e; i += 4 * B) {
        fx4 m0 = m4[i];
        fx4 m1 = m4[i + B];
        fx4 m2 = m4[i + 2 * B];
        fx4 m3 = m4[i + 3 * B];
        fx4 w0 = __builtin_nontemporal_load(&w4[i]);
        fx4 w1 = __builtin_nontemporal_load(&w4[i + B]);
        fx4 w2 = __builtin_nontemporal_load(&w4[i + 2 * B]);
        fx4 w3 = __builtin_nontemporal_load(&w4[i + 3 * B]);
        unsigned k00 = fkey(m0.x), k01 = fkey(m0.y), k02 = fkey(m0.z), k03 = fkey(m0.w);
        unsigned k10 = fkey(m1.x), k11 = fkey(m1.y), k12 = fkey(m1.z), k13 = fkey(m1.w);
        unsigned k20 = fkey(m2.x), k21 = fkey(m2.y), k22 = fkey(m2.z), k23 = fkey(m2.w);
        unsigned k30 = fkey(m3.x), k31 = fkey(m3.y), k32 = fkey(m3.z), k33 = fkey(m3.w);
        fx4 o0, o1, o2, o3;
        o0.x = (k00 >= lo) ? w0.x : 0.0f;  o0.y = (k01 >= lo) ? w0.y : 0.0f;
        o0.z = (k02 >= lo) ? w0.z : 0.0f;  o0.w = (k03 >= lo) ? w0.w : 0.0f;
        o1.x = (k10 >= lo) ? w1.x : 0.0f;  o1.y = (k11 >= lo) ? w1.y : 0.0f;
        o1.z = (k12 >= lo) ? w1.z : 0.0f;  o1.w = (k13 >= lo) ? w1.w : 0.0f;
        o2.x = (k20 >= lo) ? w2.x : 0.0f;  o2.y = (k21 >= lo) ? w2.y : 0.0f;
        o2.z = (k22 >= lo) ? w2.z : 0.0f;  o2.w = (k23 >= lo) ? w2.w : 0.0f;
        o3.x = (k30 >= lo) ? w3.x : 0.0f;  o3.y = (k31 >= lo) ? w3.y : 0.0f;
        o3.z = (k32 >= lo) ? w3.z : 0.0f;  o3.w = (k33 >= lo) ? w3.w : 0.0f;
        __builtin_nontemporal_store(o0, &o4[i]);
        __builtin_nontemporal_store(o1, &o4[i + B]);
        __builtin_nontemporal_store(o2, &o4[i + 2 * B]);
        __builtin_nontemporal_store(o3, &o4[i + 3 * B]);
        // rare: any lane has an element in the threshold bin -> slow path (1 branch/iter)
        bool anyc = ((k00 >> KEY_SHIFT) == b1u) | ((k01 >> KEY_SHIFT) == b1u) |
                    ((k02 >> KEY_SHIFT) == b1u) | ((k03 >> KEY_SHIFT) == b1u) |
                    ((k10 >> KEY_SHIFT) == b1u) | ((k11 >> KEY_SHIFT) == b1u) |
                    ((k12 >> KEY_SHIFT) == b1u) | ((k13 >> KEY_SHIFT) == b1u) |
                    ((k20 >> KEY_SHIFT) == b1u) | ((k21 >> KEY_SHIFT) == b1u) |
                    ((k22 >> KEY_SHIFT) == b1u) | ((k23 >> KEY_SHIFT) == b1u) |
                    ((k30 >> KEY_SHIFT) == b1u) | ((k31 >> KEY_SHIFT) == b1u) |
                    ((k32 >> KEY_SHIFT) == b1u) | ((k33 >> KEY_SHIFT) == b1u);
        if (__any(anyc)) {
            cand4(k00, k01, k02, k03, (unsigned)(i * 4), b1u, ctrl, list, cap);
            cand4(k10, k11, k12, k13, (unsigned)((i + B) * 4), b1u, ctrl, list, cap);
            cand4(k20, k21, k22, k23, (unsigned)((i + 2 * B) * 4), b1u, ctrl, list, cap);
            cand4(k30, k31, k32, k33, (unsigned)((i + 3 * B) * 4), b1u, ctrl, list, cap);
        }
    }
    for (; i < e; i += B) {
        fx4 m0 = m4[i];
        fx4 w0 = __builtin_nontemporal_load(&w4[i]);
        unsigned k00 = fkey(m0.x), k01 = fkey(m0.y), k02 = fkey(m0.z), k03 = fkey(m0.w);
        fx4 o0;
        o0.x = (k00 >= lo) ? w0.x : 0.0f;  o0.y = (k01 >= lo) ? w0.y : 0.0f;
        o0.z = (k02 >= lo) ? w0.z : 0.0f;  o0.w = (k03 >= lo) ? w0.w : 0.0f;
        __builtin_nontemporal_store(o0, &o4[i]);
        bool anyc = ((k00 >> KEY_SHIFT) == b1u) | ((k01 >> KEY_SHIFT) == b1u) |
                    ((k02 >> KEY_SHIFT) == b1u) | ((k03 >> KEY_SHIFT) == b1u);
        if (__any(anyc))
            cand4(k00, k01, k02, k03, (unsigned)(i * 4), b1u, ctrl, list, cap);
    }
    if (blockIdx.x == 0 && threadIdx.x == 0) {
        for (long long t = n4 * 4; t < n; ++t) {
            unsigned key = fkey(mask[t]);
            out[t] = (key >= lo) ? w[t] : 0.0f;
            if ((key >> KEY_SHIFT) == b1u) {
                unsigned p = atomicAdd(&ctrl->counter, 1u);
                if (p < cap) list[p] = make_uint2(key, (unsigned)t);
            }
        }
    }
}

// ---------------- K4: exact rank among candidates, zero first r1 ----------------
__global__ void k_fix(float* __restrict__ out, const Ctrl* __restrict__ ctrl,
                      const uint2* __restrict__ list, unsigned cap) {
    __shared__ uint2 ch[1024];
    unsigned nc = ctrl->counter;
    if (nc > cap) nc = cap;
    const long long r1 = ctrl->r1;
    if (ctrl->b1 < 0 || r1 <= 0) return;

    for (unsigned jb = 0; jb < nc; jb += blockDim.x) {
        unsigned j = jb + threadIdx.x;
        bool act = (j < nc);
        unsigned kj = 0, ij = 0;
        if (act) { uint2 e = list[j]; kj = e.x; ij = e.y; }
        long long rank = 0;
        for (unsigned cb = 0; cb < nc; cb += 1024) {
            unsigned mlen = nc - cb; if (mlen > 1024) mlen = 1024;
            for (unsigned u = threadIdx.x; u < mlen; u += blockDim.x) ch[u] = list[cb + u];
            __syncthreads();
            if (act) {
                for (unsigned u = 0; u < mlen; ++u) {
                    uint2 e = ch[u];
                    rank += (long long)((e.x < kj) || (e.x == kj && e.y < ij));
                }
            }
            __syncthreads();
        }
        if (act && rank < r1) out[ij] = 0.0f;
    }
}

extern "C" void kernel_launch(void* const* d_in, const int* in_sizes, int n_in,
                              void* d_out, int out_size, void* d_ws, size_t ws_size,
                              hipStream_t stream) {
    const float* weight = (const float*)d_in[0];
    const float* maskw  = (const float*)d_in[1];
    const float* pptr   = (const float*)d_in[2];
    float* out = (float*)d_out;
    const long long n = (long long)in_sizes[0];

    unsigned char* ws = (unsigned char*)d_ws;
    unsigned* hist = (unsigned*)ws;
    Ctrl* ctrl = (Ctrl*)(ws + 16384);
    uint2* list = (uint2*)(ws + 16416);
    size_t cap_sz = (ws_size > 16416) ? (ws_size - 16416) / sizeof(uint2) : 0;
    unsigned cap = (unsigned)(cap_sz > (size_t)(1u << 20) ? (1u << 20) : cap_sz);

    k_zero<<<(NBINS + 255) / 256, 256, 0, stream>>>(hist, ctrl);
    k_hist<<<512, 1024, 0, stream>>>(maskw, n, hist);
    k_scan<<<1, 256, 0, stream>>>(hist, ctrl, pptr, n);
    k_apply<<<2048, 256, 0, stream>>>(weight, maskw, out, n, ctrl, list, cap);
    k_fix<<<1, 256, 0, stream>>>(out, ctrl, list, cap);
}